// Round 1
// baseline (193.736 us; speedup 1.0000x reference)
//
#include <hip/hip_runtime.h>
#include <hip/hip_bf16.h>

// LSTM: SEQ=64, IN=100000, H=50 (4H=200 gates)
// x[64,100000] f32, Wi[100000,200] f32, bi[200], Wh[50,200], bh[200] -> h[50]
//
// K1: split-K GEMM via MFMA 32x32x16 bf16, hi/lo-split fp32 emulation
//     (f = bf16hi + bf16lo; x*w = xh*wh + xh*wl + xl*wh, ~2^-17 rel err).
//     R8: double-buffered LDS (46->92 KB, still 1 block/CU) so stage(t+1)
//     overlaps MFMA(t); loads issued 2 tiles ahead; 1 barrier/tile (was 2).
//     Removes the ~600-1000 cyc/tile window with zero outstanding loads.
//     8 waves: wave = stile*4 + gset; gset owns g-tiles {2g, 2g+1};
//     gset3 second tile dups tile 6 (no OOB), store skipped.
// K2: reduce 256 partials + bi + bh -> gates[s*200+g]
// K3: 64-step recurrence, single block. R8: per-wave h copy + redundant
//     (deterministic) cell update in every wave -> 1 barrier/step (was 2);
//     act double-buffered by step parity to keep it race-free.

#define K_DIM 100000
#define NG 200
#define NS 64
#define TK 32                    // 100000 = 32 * 3125 exactly
#define NBLK 256
#define NTILES 3125              // K_DIM / TK
#define CELLS (NS * NG)          // 12800
#define CELLS4 (CELLS / 4)       // 3200
#define ROWU 40                  // u16 per LDS row = 32 k + 8 pad = 80 B (16B-aligned)

typedef unsigned short u16;
typedef unsigned int   u32;
typedef __bf16 bf16x8 __attribute__((ext_vector_type(8)));
typedef float  f32x16 __attribute__((ext_vector_type(16)));

static __device__ __forceinline__ u32 rne16(float f) {
    u32 u = __float_as_uint(f);
    return (u + 0x7FFFu + ((u >> 16) & 1u)) >> 16;
}
static __device__ __forceinline__ void split_hl(float f, u32& h, u32& l) {
    u32 u  = __float_as_uint(f);
    u32 hb = u & 0xFFFF0000u;
    h = hb >> 16;
    l = rne16(f - __uint_as_float(hb));   // remainder exact; rne to bf16
}
static __device__ __forceinline__ void split4(float4 v, u32 h[4], u32 l[4]) {
    split_hl(v.x, h[0], l[0]); split_hl(v.y, h[1], l[1]);
    split_hl(v.z, h[2], l[2]); split_hl(v.w, h[3], l[3]);
}
static __device__ __forceinline__ f32x16 mfma_bf(uint4 a, uint4 b, f32x16 c) {
    return __builtin_amdgcn_mfma_f32_32x32x16_bf16(
        __builtin_bit_cast(bf16x8, a), __builtin_bit_cast(bf16x8, b), c, 0, 0, 0);
}

__global__ __launch_bounds__(512, 1) void k1_gemm_partial(
    const float* __restrict__ x, const float* __restrict__ Wi,
    float* __restrict__ partial)
{
    // double-buffered tiles: 2 x 46 KB = 92 KB LDS (1 block/CU either way)
    __shared__ __align__(16) u16 WH[2][224 * ROWU];   // Wi hi, [g][k]
    __shared__ __align__(16) u16 WL[2][224 * ROWU];   // Wi lo
    __shared__ __align__(16) u16 XH[2][64 * ROWU];    // x  hi, [s][k]
    __shared__ __align__(16) u16 XL[2][64 * ROWU];    // x  lo

    const int t    = threadIdx.x;
    const int lane = t & 63;
    const int wave = t >> 6;             // 0..7
    const int m    = lane & 31;          // MFMA row/col within tile
    const int h    = lane >> 5;          // k-half
    const int stile = wave >> 2;         // 0..1
    const int gset  = wave & 3;          // g-tiles {2g, 2g+1}; gset3: {6, dup6}

    // zero Wi pad rows 200..223 once, both buffers
#pragma unroll
    for (int b = 0; b < 2; ++b) {
        u32* zh = (u32*)&WH[b][200 * ROWU];
        u32* zl = (u32*)&WL[b][200 * ROWU];
        for (int i = t; i < 24 * ROWU / 2; i += 512) { zh[i] = 0; zl[i] = 0; }
    }

    // Wi staging: 400 f4-tasks (g4 0..49 x k4 0..7), threads t<400
    const int a_g4 = t >> 3;
    const int a_k4 = t & 7;
    const bool has_w = (t < 400);
    // x staging: 512 f4-tasks (s 0..63 x k4 0..7), one per thread
    const int xs0 = t >> 3, xk0 = t & 7;

    float4 wa[4], xa;
    auto do_loads = [&](int ti) {
        const size_t kt = (size_t)ti * TK;
        if (has_w) {
#pragma unroll
            for (int j = 0; j < 4; ++j)
                wa[j] = *(const float4*)(Wi + (kt + a_k4 * 4 + j) * NG + a_g4 * 4);
        }
        xa = *(const float4*)(x + (size_t)xs0 * K_DIM + kt + xk0 * 4);
    };
    auto stage_wi = [&](u16* WHp, u16* WLp) {
        u32 hw[4][4], lw[4][4];
#pragma unroll
        for (int j = 0; j < 4; ++j) split4(wa[j], hw[j], lw[j]);
#pragma unroll
        for (int j2 = 0; j2 < 4; ++j2) {   // transpose: row g=4g4+j2 gets 4 k's
            int off = (4 * a_g4 + j2) * ROWU + a_k4 * 4;
            *(uint2*)&WHp[off] = make_uint2(hw[0][j2] | (hw[1][j2] << 16),
                                            hw[2][j2] | (hw[3][j2] << 16));
            *(uint2*)&WLp[off] = make_uint2(lw[0][j2] | (lw[1][j2] << 16),
                                            lw[2][j2] | (lw[3][j2] << 16));
        }
    };
    auto stage_x = [&](u16* XHp, u16* XLp) {
        u32 hh[4], ll[4];
        split4(xa, hh, ll);
        int off = xs0 * ROWU + xk0 * 4;
        *(uint2*)&XHp[off] = make_uint2(hh[0] | (hh[1] << 16), hh[2] | (hh[3] << 16));
        *(uint2*)&XLp[off] = make_uint2(ll[0] | (ll[1] << 16), ll[2] | (ll[3] << 16));
    };

    f32x16 acc[2];
#pragma unroll
    for (int tt = 0; tt < 2; ++tt)
#pragma unroll
        for (int r = 0; r < 16; ++r) acc[tt][r] = 0.f;

    // fragment LDS offsets (u16 units)
    const int aoff = (stile * 32 + m) * ROWU + h * 8;
    int boff[2];
#pragma unroll
    for (int tt = 0; tt < 2; ++tt) {
        int gt = (gset == 3 && tt == 1) ? 6 : (2 * gset + tt);
        boff[tt] = (gt * 32 + m) * ROWU + h * 8;
    }

    // prologue: tile0 -> buf0; issue loads for tile1
    do_loads(blockIdx.x);
    if (has_w) stage_wi(WH[0], WL[0]);
    stage_x(XH[0], XL[0]);
    {
        int tin = blockIdx.x + NBLK;     // always < NTILES (511 < 3125)
        if (tin < NTILES) do_loads(tin);
    }
    __syncthreads();

    int p = 0;
    for (int ti = blockIdx.x; ti < NTILES; ti += NBLK) {
        // stage tile ti+NBLK into the idle buffer while we compute buf[p].
        // Safe: previous iteration's barrier guarantees all waves finished
        // reading buf[p^1] (they computed it last iteration).
        int tn = ti + NBLK;
        if (tn < NTILES) {
            if (has_w) stage_wi(WH[p ^ 1], WL[p ^ 1]);
            stage_x(XH[p ^ 1], XL[p ^ 1]);
            int t2 = tn + NBLK;
            if (t2 < NTILES) do_loads(t2);   // issued BEFORE MFMA: HBM stays busy
        }

        const u16* WHp = WH[p]; const u16* WLp = WL[p];
        const u16* XHp = XH[p]; const u16* XLp = XL[p];
#pragma unroll
        for (int kk = 0; kk < 2; ++kk) {
            uint4 ah = *(const uint4*)&XHp[aoff + kk * 16];
            uint4 al = *(const uint4*)&XLp[aoff + kk * 16];
#pragma unroll
            for (int tt = 0; tt < 2; ++tt) {
                uint4 bh = *(const uint4*)&WHp[boff[tt] + kk * 16];
                uint4 bl = *(const uint4*)&WLp[boff[tt] + kk * 16];
                acc[tt] = mfma_bf(ah, bh, acc[tt]);   // xh*wh
                acc[tt] = mfma_bf(ah, bl, acc[tt]);   // xh*wl
                acc[tt] = mfma_bf(al, bh, acc[tt]);   // xl*wh
            }
        }
        __syncthreads();                  // one barrier per tile (was two)
        p ^= 1;
    }

    // epilogue: partial[b][s][g]; C/D: col=lane&31, row=(r&3)+8(r>>2)+4h
    float* base = partial + (size_t)blockIdx.x * CELLS;
#pragma unroll
    for (int tt = 0; tt < 2; ++tt) {
        if (gset == 3 && tt == 1) continue;   // duplicate of tile 6
        int g = (2 * gset + tt) * 32 + m;
        if (g < NG) {
#pragma unroll
            for (int r = 0; r < 16; ++r) {
                int srow = stile * 32 + (r & 3) + 8 * (r >> 2) + 4 * h;
                base[srow * NG + g] = acc[tt][r];
            }
        }
    }
}

__global__ __launch_bounds__(512) void k2_reduce(
    const float* __restrict__ partial, const float* __restrict__ bi,
    const float* __restrict__ bh, float* __restrict__ gates)
{
    __shared__ float4 red[512];
    const int tid   = threadIdx.x;
    const int fid   = tid & 15;                 // f4-cell within block
    const int slice = tid >> 4;                 // 0..31, each sums 8 b's
    const int g4    = blockIdx.x * 16 + fid;    // 0..3199

    const float4* p4 = (const float4*)partial;
    float4 sum = make_float4(0.f, 0.f, 0.f, 0.f);
#pragma unroll 4
    for (int b = slice * 8; b < slice * 8 + 8; ++b) {
        float4 v = p4[(size_t)b * CELLS4 + g4];
        sum.x += v.x; sum.y += v.y; sum.z += v.z; sum.w += v.w;
    }
    red[tid] = sum;
    __syncthreads();
    if (tid < 16) {
        float4 tot = red[tid];
#pragma unroll
        for (int p = 1; p < 32; ++p) {
            float4 v = red[p * 16 + tid];
            tot.x += v.x; tot.y += v.y; tot.z += v.z; tot.w += v.w;
        }
        int gg = (g4 * 4) % NG;                 // NG%4==0: never wraps mid-f4
        float4 b1 = *(const float4*)(bi + gg);
        float4 b2 = *(const float4*)(bh + gg);
        tot.x += b1.x + b2.x; tot.y += b1.y + b2.y;
        tot.z += b1.z + b2.z; tot.w += b1.w + b2.w;
        ((float4*)gates)[g4] = tot;
    }
}

__global__ __launch_bounds__(256) void k3_lstm(
    const float* __restrict__ gates, const float* __restrict__ Wh,
    float* __restrict__ out)
{
    __shared__ __align__(16) float gz[CELLS];   // 51.2 KB: all gate pre-activations
    __shared__ float hbuf[4][64];               // per-WAVE h copy (no cross-wave reads)
    __shared__ float act[2][NG];                // double-buffered by step parity
    const int t    = threadIdx.x;
    const int g    = t;                         // gate index, active < 200
    const int w    = t >> 6;                    // wave 0..3
    const int lane = t & 63;

    {   // vectorized gates load
        float4* gz4 = (float4*)gz;
        const float4* gp4 = (const float4*)gates;
        for (int i = t; i < CELLS4; i += 256) gz4[i] = gp4[i];
    }

    float wh[50];
    if (g < NG) {
#pragma unroll
        for (int j = 0; j < 50; ++j) wh[j] = Wh[j * NG + g];  // coalesced column
    }
    hbuf[w][lane] = 0.f;                        // each wave zeroes its own copy
    float c = 0.f, h = 0.f;
    const bool is_cell_gate = (g >= 100 && g < 150);
    __syncthreads();

    const float* hl = hbuf[w];
    for (int s = 0; s < 64; ++s) {
        if (g < NG) {
            float a0 = gz[s * NG + g], a1 = 0.f, a2 = 0.f, a3 = 0.f;
#pragma unroll
            for (int jj = 0; jj < 48; jj += 4) {               // 12x b128 broadcast
                float4 h4 = *(const float4*)(hl + jj);
                a0 = fmaf(h4.x, wh[jj],     a0);
                a1 = fmaf(h4.y, wh[jj + 1], a1);
                a2 = fmaf(h4.z, wh[jj + 2], a2);
                a3 = fmaf(h4.w, wh[jj + 3], a3);
            }
            {
                float2 h2 = *(const float2*)(hl + 48);         // 1x b64
                a0 = fmaf(h2.x, wh[48], a0);
                a1 = fmaf(h2.y, wh[49], a1);
            }
            float z = (a0 + a1) + (a2 + a3);
            float e   = __expf(-z);
            float sig = 1.f / (1.f + e);
            float e2  = e * e;                        // e^{-2z}
            float th  = (1.f - e2) / (1.f + e2);
            act[s & 1][g] = is_cell_gate ? th : sig;
        }
        __syncthreads();    // the ONLY barrier per step: act[s&1] published.
        // Race-free: next write to act[s&1] is step s+2, which every wave
        // reaches only after barrier(s+1), by which time all step-s readers
        // consumed their values.
        if (lane < 50) {
            // redundant identical update in every wave -> no publish barrier
            float iv = act[s & 1][lane];
            float fv = act[s & 1][50 + lane];
            float gv = act[s & 1][100 + lane];
            float ov = act[s & 1][150 + lane];
            c = fmaf(fv, c, iv * gv);
            float e2c = __expf(-2.f * c);
            h = ov * (1.f - e2c) / (1.f + e2c);
            hbuf[w][lane] = h;          // own-wave copy; in-order LDS per wave
        }
    }
    if (t < 50) out[t] = h;
}

extern "C" void kernel_launch(void* const* d_in, const int* in_sizes, int n_in,
                              void* d_out, int out_size, void* d_ws, size_t ws_size,
                              hipStream_t stream)
{
    const float* x  = (const float*)d_in[0];
    const float* Wi = (const float*)d_in[1];
    const float* bi = (const float*)d_in[2];
    const float* Wh = (const float*)d_in[3];
    const float* bh = (const float*)d_in[4];
    float* out = (float*)d_out;

    float* partial = (float*)d_ws;                    // 256*12800 f32 = 13.1 MB
    float* gates   = partial + (size_t)NBLK * CELLS;  // 12800 f32

    k1_gemm_partial<<<NBLK, 512, 0, stream>>>(x, Wi, partial);
    k2_reduce<<<CELLS4 / 16, 512, 0, stream>>>(partial, bi, bh, gates);
    k3_lstm<<<1, 256, 0, stream>>>(gates, Wh, out);
}

// Round 2
// 184.795 us; speedup vs baseline: 1.0484x; 1.0484x over previous
//
#include <hip/hip_runtime.h>
#include <hip/hip_bf16.h>

// LSTM: SEQ=64, IN=100000, H=50 (4H=200 gates)
// x[64,100000] f32, Wi[100000,200] f32, bi[200], Wh[50,200], bh[200] -> h[50]
//
// K1: split-K GEMM via MFMA 32x32x16 bf16, hi/lo-split fp32 emulation
//     (f = bf16hi + bf16lo; x*w = xh*wh + xh*wl + xl*wh, ~2^-17 rel err).
//     R9: TRUE 2-deep load pipeline. Dual register sets A/B each hold one
//     in-flight tile; staging set A waits only A's loads while B's remain
//     outstanding -> HBM never idle during the split/pack VALU phase.
//     (R8's single regset still drained vmcnt to 0 before reissuing: the
//     idle gap == stage time, ~600 cyc/tile, ~15% of the 3.2k-cyc HBM
//     service time per tile per CU.)  Double LDS buffer, 1 barrier/tile,
//     loop unrolled x2 so regset parity is compile-time (no scratch).
//     8 waves: wave = stile*4 + gset; gset owns g-tiles {2g, 2g+1};
//     gset3 second tile dups tile 6 (no OOB), store skipped.
// K2: reduce 256 partials + bi + bh -> gates[s*200+g]
// K3: 64-step recurrence, single block, gates in LDS (proven R0 version).

#define K_DIM 100000
#define NG 200
#define NS 64
#define TK 32                    // 100000 = 32 * 3125 exactly
#define NBLK 256
#define NTILES 3125              // K_DIM / TK
#define CELLS (NS * NG)          // 12800
#define CELLS4 (CELLS / 4)       // 3200
#define ROWU 40                  // u16 per LDS row = 32 k + 8 pad = 80 B (16B-aligned)

typedef unsigned short u16;
typedef unsigned int   u32;
typedef __bf16 bf16x8 __attribute__((ext_vector_type(8)));
typedef float  f32x16 __attribute__((ext_vector_type(16)));

static __device__ __forceinline__ u32 rne16(float f) {
    u32 u = __float_as_uint(f);
    return (u + 0x7FFFu + ((u >> 16) & 1u)) >> 16;
}
static __device__ __forceinline__ void split_hl(float f, u32& h, u32& l) {
    u32 u  = __float_as_uint(f);
    u32 hb = u & 0xFFFF0000u;
    h = hb >> 16;
    l = rne16(f - __uint_as_float(hb));   // remainder exact; rne to bf16
}
static __device__ __forceinline__ void split4(float4 v, u32 h[4], u32 l[4]) {
    split_hl(v.x, h[0], l[0]); split_hl(v.y, h[1], l[1]);
    split_hl(v.z, h[2], l[2]); split_hl(v.w, h[3], l[3]);
}
static __device__ __forceinline__ f32x16 mfma_bf(uint4 a, uint4 b, f32x16 c) {
    return __builtin_amdgcn_mfma_f32_32x32x16_bf16(
        __builtin_bit_cast(bf16x8, a), __builtin_bit_cast(bf16x8, b), c, 0, 0, 0);
}

__global__ __launch_bounds__(512, 1) void k1_gemm_partial(
    const float* __restrict__ x, const float* __restrict__ Wi,
    float* __restrict__ partial)
{
    // double-buffered tiles: 2 x 46 KB = 92 KB LDS (1 block/CU either way)
    __shared__ __align__(16) u16 WH[2][224 * ROWU];   // Wi hi, [g][k]
    __shared__ __align__(16) u16 WL[2][224 * ROWU];   // Wi lo
    __shared__ __align__(16) u16 XH[2][64 * ROWU];    // x  hi, [s][k]
    __shared__ __align__(16) u16 XL[2][64 * ROWU];    // x  lo

    const int t    = threadIdx.x;
    const int lane = t & 63;
    const int wave = t >> 6;             // 0..7
    const int m    = lane & 31;          // MFMA row/col within tile
    const int h    = lane >> 5;          // k-half
    const int stile = wave >> 2;         // 0..1
    const int gset  = wave & 3;          // g-tiles {2g, 2g+1}; gset3: {6, dup6}

    // zero Wi pad rows 200..223 once, both buffers
#pragma unroll
    for (int b = 0; b < 2; ++b) {
        u32* zh = (u32*)&WH[b][200 * ROWU];
        u32* zl = (u32*)&WL[b][200 * ROWU];
        for (int i = t; i < 24 * ROWU / 2; i += 512) { zh[i] = 0; zl[i] = 0; }
    }

    // Wi staging: 400 f4-tasks (g4 0..49 x k4 0..7), threads t<400
    const int a_g4 = t >> 3;
    const int a_k4 = t & 7;
    const bool has_w = (t < 400);
    // x staging: 512 f4-tasks (s 0..63 x k4 0..7), one per thread
    const int xs0 = t >> 3, xk0 = t & 7;

    auto do_loads = [&](int ti, float4 (&wr)[4], float4& xr) {
        const size_t kt = (size_t)ti * TK;
        if (has_w) {
#pragma unroll
            for (int j = 0; j < 4; ++j)
                wr[j] = *(const float4*)(Wi + (kt + a_k4 * 4 + j) * NG + a_g4 * 4);
        }
        xr = *(const float4*)(x + (size_t)xs0 * K_DIM + kt + xk0 * 4);
    };
    auto stage_wi = [&](const float4 (&r)[4], u16* WHp, u16* WLp) {
        u32 hw[4][4], lw[4][4];
#pragma unroll
        for (int j = 0; j < 4; ++j) split4(r[j], hw[j], lw[j]);
#pragma unroll
        for (int j2 = 0; j2 < 4; ++j2) {   // transpose: row g=4g4+j2 gets 4 k's
            int off = (4 * a_g4 + j2) * ROWU + a_k4 * 4;
            *(uint2*)&WHp[off] = make_uint2(hw[0][j2] | (hw[1][j2] << 16),
                                            hw[2][j2] | (hw[3][j2] << 16));
            *(uint2*)&WLp[off] = make_uint2(lw[0][j2] | (lw[1][j2] << 16),
                                            lw[2][j2] | (lw[3][j2] << 16));
        }
    };
    auto stage_x = [&](float4 v, u16* XHp, u16* XLp) {
        u32 hh[4], ll[4];
        split4(v, hh, ll);
        int off = xs0 * ROWU + xk0 * 4;
        *(uint2*)&XHp[off] = make_uint2(hh[0] | (hh[1] << 16), hh[2] | (hh[3] << 16));
        *(uint2*)&XLp[off] = make_uint2(ll[0] | (ll[1] << 16), ll[2] | (ll[3] << 16));
    };

    f32x16 acc[2];
#pragma unroll
    for (int tt = 0; tt < 2; ++tt)
#pragma unroll
        for (int r = 0; r < 16; ++r) acc[tt][r] = 0.f;

    // fragment LDS offsets (u16 units)
    const int aoff = (stile * 32 + m) * ROWU + h * 8;
    int boff[2];
#pragma unroll
    for (int tt = 0; tt < 2; ++tt) {
        int gt = (gset == 3 && tt == 1) ? 6 : (2 * gset + tt);
        boff[tt] = (gt * 32 + m) * ROWU + h * 8;
    }

    auto mfma_phase = [&](int p) {
        const u16* WHp = WH[p]; const u16* WLp = WL[p];
        const u16* XHp = XH[p]; const u16* XLp = XL[p];
#pragma unroll
        for (int kk = 0; kk < 2; ++kk) {
            uint4 ah = *(const uint4*)&XHp[aoff + kk * 16];
            uint4 al = *(const uint4*)&XLp[aoff + kk * 16];
#pragma unroll
            for (int tt = 0; tt < 2; ++tt) {
                uint4 bh = *(const uint4*)&WHp[boff[tt] + kk * 16];
                uint4 bl = *(const uint4*)&WLp[boff[tt] + kk * 16];
                acc[tt] = mfma_bf(ah, bh, acc[tt]);   // xh*wh
                acc[tt] = mfma_bf(ah, bl, acc[tt]);   // xh*wl
                acc[tt] = mfma_bf(al, bh, acc[tt]);   // xl*wh
            }
        }
    };

    // ---- prologue: A<-t0, B<-t1; stage A->buf0; A<-t2 (all guards trivially
    //      true: ti0+2*NBLK <= 767 < 3125) ----
    float4 waA[4], waB[4];
    float4 xaA, xaB;
    const int ti0 = blockIdx.x;
    do_loads(ti0,            waA, xaA);
    do_loads(ti0 + NBLK,     waB, xaB);
    if (has_w) stage_wi(waA, WH[0], WL[0]);
    stage_x(xaA, XH[0], XL[0]);
    do_loads(ti0 + 2 * NBLK, waA, xaA);
    __syncthreads();

    // ---- main loop: body for tile ti consumes buf[p]; stages the OTHER
    //      regset (holding tile ti+NBLK) into buf[p^1]; reissues loads for
    //      tile ti+3*NBLK into that same set. While one set is being staged
    //      (vmcnt wait on its loads), the other set's loads stay in flight:
    //      HBM has outstanding requests at all times. ----
    int p = 0;
    int ti = ti0;
    while (ti < NTILES) {
        {   // body: compute ti, stage from B
            int tn = ti + NBLK;
            if (tn < NTILES) {
                if (has_w) stage_wi(waB, WH[p ^ 1], WL[p ^ 1]);
                stage_x(xaB, XH[p ^ 1], XL[p ^ 1]);
                int tf = tn + 2 * NBLK;
                if (tf < NTILES) do_loads(tf, waB, xaB);
            }
            mfma_phase(p);
            __syncthreads();
            p ^= 1; ti += NBLK;
        }
        if (ti >= NTILES) break;
        {   // body: compute ti, stage from A
            int tn = ti + NBLK;
            if (tn < NTILES) {
                if (has_w) stage_wi(waA, WH[p ^ 1], WL[p ^ 1]);
                stage_x(xaA, XH[p ^ 1], XL[p ^ 1]);
                int tf = tn + 2 * NBLK;
                if (tf < NTILES) do_loads(tf, waA, xaA);
            }
            mfma_phase(p);
            __syncthreads();
            p ^= 1; ti += NBLK;
        }
    }

    // epilogue: partial[b][s][g]; C/D: col=lane&31, row=(r&3)+8(r>>2)+4h
    float* base = partial + (size_t)blockIdx.x * CELLS;
#pragma unroll
    for (int tt = 0; tt < 2; ++tt) {
        if (gset == 3 && tt == 1) continue;   // duplicate of tile 6
        int g = (2 * gset + tt) * 32 + m;
        if (g < NG) {
#pragma unroll
            for (int r = 0; r < 16; ++r) {
                int srow = stile * 32 + (r & 3) + 8 * (r >> 2) + 4 * h;
                base[srow * NG + g] = acc[tt][r];
            }
        }
    }
}

__global__ __launch_bounds__(512) void k2_reduce(
    const float* __restrict__ partial, const float* __restrict__ bi,
    const float* __restrict__ bh, float* __restrict__ gates)
{
    __shared__ float4 red[512];
    const int tid   = threadIdx.x;
    const int fid   = tid & 15;                 // f4-cell within block
    const int slice = tid >> 4;                 // 0..31, each sums 8 b's
    const int g4    = blockIdx.x * 16 + fid;    // 0..3199

    const float4* p4 = (const float4*)partial;
    float4 sum = make_float4(0.f, 0.f, 0.f, 0.f);
#pragma unroll 4
    for (int b = slice * 8; b < slice * 8 + 8; ++b) {
        float4 v = p4[(size_t)b * CELLS4 + g4];
        sum.x += v.x; sum.y += v.y; sum.z += v.z; sum.w += v.w;
    }
    red[tid] = sum;
    __syncthreads();
    if (tid < 16) {
        float4 tot = red[tid];
#pragma unroll
        for (int p = 1; p < 32; ++p) {
            float4 v = red[p * 16 + tid];
            tot.x += v.x; tot.y += v.y; tot.z += v.z; tot.w += v.w;
        }
        int gg = (g4 * 4) % NG;                 // NG%4==0: never wraps mid-f4
        float4 b1 = *(const float4*)(bi + gg);
        float4 b2 = *(const float4*)(bh + gg);
        tot.x += b1.x + b2.x; tot.y += b1.y + b2.y;
        tot.z += b1.z + b2.z; tot.w += b1.w + b2.w;
        ((float4*)gates)[g4] = tot;
    }
}

__global__ __launch_bounds__(256) void k3_lstm(
    const float* __restrict__ gates, const float* __restrict__ Wh,
    float* __restrict__ out)
{
    __shared__ float gz[CELLS];     // 51.2 KB: all gate pre-activations
    __shared__ float h_lds[64];
    __shared__ float act_lds[NG];
    const int g = threadIdx.x;      // gate index, active < 200

    for (int i = g; i < CELLS; i += 256) gz[i] = gates[i];

    float wh[50];
    if (g < NG) {
#pragma unroll
        for (int j = 0; j < 50; ++j) wh[j] = Wh[j * NG + g];  // coalesced column
    }
    if (g < 64) h_lds[g] = 0.f;
    float c = 0.f, h = 0.f;
    const bool is_cell_gate = (g >= 100 && g < 150);
    __syncthreads();

    for (int s = 0; s < 64; ++s) {
        if (g < NG) {
            float a0 = gz[s * NG + g], a1 = 0.f, a2 = 0.f, a3 = 0.f;
#pragma unroll
            for (int jj = 0; jj < 48; jj += 4) {               // 12x b128 broadcast
                float4 h4 = *(const float4*)(h_lds + jj);
                a0 = fmaf(h4.x, wh[jj],     a0);
                a1 = fmaf(h4.y, wh[jj + 1], a1);
                a2 = fmaf(h4.z, wh[jj + 2], a2);
                a3 = fmaf(h4.w, wh[jj + 3], a3);
            }
            {
                float2 h2 = *(const float2*)(h_lds + 48);      // 1x b64
                a0 = fmaf(h2.x, wh[48], a0);
                a1 = fmaf(h2.y, wh[49], a1);
            }
            float z = (a0 + a1) + (a2 + a3);
            float e   = __expf(-z);
            float sig = 1.f / (1.f + e);
            float e2  = e * e;                        // e^{-2z}
            float th  = (1.f - e2) / (1.f + e2);
            act_lds[g] = is_cell_gate ? th : sig;
        }
        __syncthreads();
        if (g < 50) {
            float iv = act_lds[g];
            float fv = act_lds[50 + g];
            float gv = act_lds[100 + g];
            float ov = act_lds[150 + g];
            c = fmaf(fv, c, iv * gv);
            float e2c = __expf(-2.f * c);
            h = ov * (1.f - e2c) / (1.f + e2c);
            h_lds[g] = h;
        }
        __syncthreads();
    }
    if (g < 50) out[g] = h;
}

extern "C" void kernel_launch(void* const* d_in, const int* in_sizes, int n_in,
                              void* d_out, int out_size, void* d_ws, size_t ws_size,
                              hipStream_t stream)
{
    const float* x  = (const float*)d_in[0];
    const float* Wi = (const float*)d_in[1];
    const float* bi = (const float*)d_in[2];
    const float* Wh = (const float*)d_in[3];
    const float* bh = (const float*)d_in[4];
    float* out = (float*)d_out;

    float* partial = (float*)d_ws;                    // 256*12800 f32 = 13.1 MB
    float* gates   = partial + (size_t)NBLK * CELLS;  // 12800 f32

    k1_gemm_partial<<<NBLK, 512, 0, stream>>>(x, Wi, partial);
    k2_reduce<<<CELLS4 / 16, 512, 0, stream>>>(partial, bi, bh, gates);
    k3_lstm<<<1, 256, 0, stream>>>(gates, Wh, out);
}